// Round 5
// baseline (19050.833 us; speedup 1.0000x reference)
//
#include <hip/hip_runtime.h>
#include <math.h>

// LSTM encode, round 5: persistent cooperative kernel.
// One launch: 256 blocks (1/CU) x 256 threads (4 waves), loop over 512 timesteps
// inside the kernel. Per-step cross-block sync = 8 independent 32-block
// sense-reversing barriers (one per mb group; only blocks sharing batch rows
// exchange h). bf16x3 split MFMA as rounds 2-4. Bhi staged in LDS once (84 KB),
// Blo streamed from L2, c state in registers, bias in registers.

#define HIDDEN 512
#define TSTEPS 512
#define BATCH 256
#define FEATD 128
#define ACTD 32
#define DIMD 160
#define GATES 2048
#define NKT 21
#define NGROUPS 32
#define NFRAGS (NGROUPS * NKT * 4)   // 2688

#define SB 74                 // zbuf stride per b-row (f32)
#define SW (32 * SB)          // zbuf stride per wave

typedef short bf16x8 __attribute__((ext_vector_type(8)));
typedef float f32x4 __attribute__((ext_vector_type(4)));

__device__ __forceinline__ unsigned short f2bf(float v) {
    union { float f; unsigned u; } c; c.f = v;
    unsigned r = c.u + 0x7fffu + ((c.u >> 16) & 1u);
    return (unsigned short)(r >> 16);
}
__device__ __forceinline__ float bf2f(unsigned short s) {
    union { unsigned u; float f; } c; c.u = ((unsigned)s) << 16; return c.f;
}
__device__ __forceinline__ float fast_sigmoid(float x) {
    return 1.0f / (1.0f + __expf(-x));
}
__device__ __forceinline__ float fast_tanh(float x) {
    return 1.0f - 2.0f / (__expf(2.0f * x) + 1.0f);
}

// ---- pack [W;U] (672 x 2048 fp32) into B-fragment-ordered hi/lo bf16 -------
// frag f = (ng*NKT + kt)*4 + tc; element (lane,j) = B[k][col],
// k = kt*32 + (lane>>4)*8 + j, col = tc*512 + ng*16 + (lane&15).
__global__ __launch_bounds__(256)
void pack_weights(const float* __restrict__ W, const float* __restrict__ U,
                  unsigned short* __restrict__ Bhi, unsigned short* __restrict__ Blo)
{
    const int idx = blockIdx.x * 256 + threadIdx.x;
    if (idx >= NFRAGS * 64) return;
    const int lane = idx & 63;
    const int f = idx >> 6;
    const int tc = f & 3;
    const int kt = (f >> 2) % NKT;
    const int ng = (f >> 2) / NKT;
    const int col = tc * HIDDEN + ng * 16 + (lane & 15);
    const int kbase = kt * 32 + (lane >> 4) * 8;
    #pragma unroll
    for (int j = 0; j < 8; ++j) {
        const int k = kbase + j;
        const float v = (k < DIMD) ? W[(size_t)k * GATES + col]
                                   : U[(size_t)(k - DIMD) * GATES + col];
        const unsigned short hi = f2bf(v);
        Bhi[(size_t)idx * 8 + j] = hi;
        Blo[(size_t)idx * 8 + j] = f2bf(v - bf2f(hi));
    }
}

__device__ __forceinline__ void mfma_tile_lds(const bf16x8* ahi, const bf16x8* alo,
                                              const unsigned short* bh_lds,
                                              const unsigned short* bl_glb,
                                              f32x4 (&acc)[2][4])
{
    #pragma unroll
    for (int tc = 0; tc < 4; ++tc) {
        const bf16x8 bhv = *(const bf16x8*)(bh_lds + tc * 512);
        const bf16x8 blv = *(const bf16x8*)(bl_glb + tc * 512);
        #pragma unroll
        for (int mg = 0; mg < 2; ++mg) {
            acc[mg][tc] = __builtin_amdgcn_mfma_f32_16x16x32_bf16(ahi[mg], bhv, acc[mg][tc], 0, 0, 0);
            acc[mg][tc] = __builtin_amdgcn_mfma_f32_16x16x32_bf16(alo[mg], bhv, acc[mg][tc], 0, 0, 0);
            acc[mg][tc] = __builtin_amdgcn_mfma_f32_16x16x32_bf16(ahi[mg], blv, acc[mg][tc], 0, 0, 0);
        }
    }
}

__global__ __launch_bounds__(256, 1)
void lstm_persistent(const float* __restrict__ feat, const float* __restrict__ act,
                     const unsigned short* __restrict__ Bhi,
                     const unsigned short* __restrict__ Blo,
                     const float* __restrict__ bias,
                     unsigned short* __restrict__ h_hi0,
                     unsigned short* __restrict__ h_lo0,
                     unsigned short* __restrict__ h_hi1,
                     unsigned short* __restrict__ h_lo1,
                     float* __restrict__ out,
                     int* __restrict__ bar)
{
    __shared__ unsigned short lds_bhi[84 * 512];   // 86016 B
    __shared__ float zbuf[4 * SW];                 // 37888 B  (total 121 KB)

    const int tid = threadIdx.x;
    const int lane = tid & 63;
    const int w = tid >> 6;
    const int ng = blockIdx.x;
    const int mb = blockIdx.y;
    const int m0 = mb * 32;
    const int u0 = ng * 16;
    const int kg = lane >> 4;
    const int nn = lane & 15;

    // ---- stage my Bhi slab (84 frags = 86016 B) into LDS -------------------
    {
        const uint4* src = (const uint4*)(Bhi + (size_t)ng * 84 * 512);
        uint4* dst = (uint4*)lds_bhi;
        #pragma unroll
        for (int i = 0; i < 21; ++i)
            dst[tid + 256 * i] = src[tid + 256 * i];
    }

    // ---- epilogue-role constants: bias + c state in registers --------------
    const int bl_ = tid >> 3;           // 0..31 (batch row in tile)
    const int n0 = (tid & 7) * 2;       // 0..14 (unit pair)
    const int u = u0 + n0;
    float br[4][2];
    #pragma unroll
    for (int g = 0; g < 4; ++g) {
        br[g][0] = bias[g * HIDDEN + u];
        br[g][1] = bias[g * HIDDEN + u + 1];
    }
    float c0 = 0.f, c1 = 0.f;
    const size_t oidx = (size_t)(m0 + bl_) * HIDDEN + u;

    int* const cnt_p  = bar + mb * 32;
    int* const flag_p = bar + mb * 32 + 1;
    int sense = 0;

    __syncthreads();   // LDS Bhi ready

    for (int t = 0; t < TSTEPS; ++t) {
        const unsigned short* hin_hi = (t & 1) ? h_hi1 : h_hi0;
        const unsigned short* hin_lo = (t & 1) ? h_lo1 : h_lo0;
        unsigned short* hout_hi = (t & 1) ? h_hi0 : h_hi1;
        unsigned short* hout_lo = (t & 1) ? h_lo0 : h_lo1;

        f32x4 acc[2][4];
        #pragma unroll
        for (int mg = 0; mg < 2; ++mg)
            #pragma unroll
            for (int tc = 0; tc < 4; ++tc)
                acc[mg][tc] = (f32x4){0.f, 0.f, 0.f, 0.f};

        if (w == 0) {
            // x tiles kt 0..4: fp32 load + hi/lo split on the fly
            #pragma unroll
            for (int kt = 0; kt < 5; ++kt) {
                bf16x8 ahi[2], alo[2];
                #pragma unroll
                for (int mg = 0; mg < 2; ++mg) {
                    const int b = m0 + mg * 16 + nn;
                    const float* src = (kt < 4)
                        ? feat + ((size_t)b * TSTEPS + t) * FEATD + kt * 32 + kg * 8
                        : act  + ((size_t)b * TSTEPS + t) * ACTD  + kg * 8;
                    const float4 v0 = *(const float4*)src;
                    const float4 v1 = *(const float4*)(src + 4);
                    const float vv[8] = {v0.x, v0.y, v0.z, v0.w, v1.x, v1.y, v1.z, v1.w};
                    #pragma unroll
                    for (int j = 0; j < 8; ++j) {
                        const unsigned short h = f2bf(vv[j]);
                        ahi[mg][j] = (short)h;
                        alo[mg][j] = (short)f2bf(vv[j] - bf2f(h));
                    }
                }
                mfma_tile_lds(ahi, alo,
                              lds_bhi + (kt * 4) * 512 + lane * 8,
                              Blo + (size_t)(ng * NKT + kt) * 2048 + lane * 8, acc);
            }
            {   // h tile kt=5
                bf16x8 ahi[2], alo[2];
                #pragma unroll
                for (int mg = 0; mg < 2; ++mg) {
                    const int b = m0 + mg * 16 + nn;
                    ahi[mg] = *(const bf16x8*)(hin_hi + (size_t)b * HIDDEN + kg * 8);
                    alo[mg] = *(const bf16x8*)(hin_lo + (size_t)b * HIDDEN + kg * 8);
                }
                mfma_tile_lds(ahi, alo,
                              lds_bhi + (5 * 4) * 512 + lane * 8,
                              Blo + (size_t)(ng * NKT + 5) * 2048 + lane * 8, acc);
            }
        } else {
            const int kt0 = 1 + w * 5;    // w1:6..10  w2:11..15  w3:16..20
            #pragma unroll
            for (int i = 0; i < 5; ++i) {
                const int kt = kt0 + i;
                const int hk = kt * 32 - DIMD + kg * 8;
                bf16x8 ahi[2], alo[2];
                #pragma unroll
                for (int mg = 0; mg < 2; ++mg) {
                    const int b = m0 + mg * 16 + nn;
                    ahi[mg] = *(const bf16x8*)(hin_hi + (size_t)b * HIDDEN + hk);
                    alo[mg] = *(const bf16x8*)(hin_lo + (size_t)b * HIDDEN + hk);
                }
                mfma_tile_lds(ahi, alo,
                              lds_bhi + (kt * 4) * 512 + lane * 8,
                              Blo + (size_t)(ng * NKT + kt) * 2048 + lane * 8, acc);
            }
        }

        // ---- partials -> LDS ------------------------------------------------
        #pragma unroll
        for (int mg = 0; mg < 2; ++mg)
            #pragma unroll
            for (int tc = 0; tc < 4; ++tc)
                #pragma unroll
                for (int r = 0; r < 4; ++r)
                    zbuf[w * SW + (mg * 16 + kg * 4 + r) * SB + tc * 16 + nn] = acc[mg][tc][r];
        __syncthreads();

        // ---- reduce + gates; c in regs --------------------------------------
        float zg_[4][2];
        #pragma unroll
        for (int g = 0; g < 4; ++g) {
            float2 s = {0.f, 0.f};
            #pragma unroll
            for (int ww = 0; ww < 4; ++ww) {
                const float2 v = *(const float2*)&zbuf[ww * SW + bl_ * SB + g * 16 + n0];
                s.x += v.x; s.y += v.y;
            }
            zg_[g][0] = s.x; zg_[g][1] = s.y;
        }
        const float ig0 = fast_sigmoid(zg_[0][0] + br[0][0]);
        const float fg0 = fast_sigmoid(zg_[1][0] + br[1][0]);
        const float gg0 = fast_tanh   (zg_[2][0] + br[2][0]);
        const float og0 = fast_sigmoid(zg_[3][0] + br[3][0]);
        const float ig1 = fast_sigmoid(zg_[0][1] + br[0][1]);
        const float fg1 = fast_sigmoid(zg_[1][1] + br[1][1]);
        const float gg1 = fast_tanh   (zg_[2][1] + br[2][1]);
        const float og1 = fast_sigmoid(zg_[3][1] + br[3][1]);
        c0 = fg0 * c0 + ig0 * gg0;
        c1 = fg1 * c1 + ig1 * gg1;
        const float hv0 = og0 * fast_tanh(c0);
        const float hv1 = og1 * fast_tanh(c1);
        const unsigned short h0 = f2bf(hv0), h1 = f2bf(hv1);
        *(unsigned*)&hout_hi[oidx] = (unsigned)h0 | ((unsigned)h1 << 16);
        const unsigned short l0 = f2bf(hv0 - bf2f(h0)), l1 = f2bf(hv1 - bf2f(h1));
        *(unsigned*)&hout_lo[oidx] = (unsigned)l0 | ((unsigned)l1 << 16);
        if (t == TSTEPS - 1) *(float2*)&out[oidx] = (float2){hv0, hv1};

        // ---- inter-block barrier (32 blocks of this mb group) ---------------
        __syncthreads();                 // all h-writes of the block issued
        sense ^= 1;
        if (tid == 0) {
            __threadfence();             // release h-writes (agent scope)
            const int arrived = __hip_atomic_fetch_add(cnt_p, 1, __ATOMIC_ACQ_REL,
                                                       __HIP_MEMORY_SCOPE_AGENT);
            if (arrived == NGROUPS - 1) {
                __hip_atomic_store(cnt_p, 0, __ATOMIC_RELAXED, __HIP_MEMORY_SCOPE_AGENT);
                __hip_atomic_store(flag_p, sense, __ATOMIC_RELEASE, __HIP_MEMORY_SCOPE_AGENT);
            } else {
                while (__hip_atomic_load(flag_p, __ATOMIC_ACQUIRE,
                                         __HIP_MEMORY_SCOPE_AGENT) != sense) { }
            }
            __threadfence();             // acquire: invalidate stale h lines
        }
        __syncthreads();                 // release whole block past the barrier
    }
}

extern "C" void kernel_launch(void* const* d_in, const int* in_sizes, int n_in,
                              void* d_out, int out_size, void* d_ws, size_t ws_size,
                              hipStream_t stream) {
    const float* features = (const float*)d_in[0];
    const float* actions  = (const float*)d_in[1];
    const float* W        = (const float*)d_in[2];
    const float* U        = (const float*)d_in[3];
    const float* bias     = (const float*)d_in[4];
    float* out = (float*)d_out;

    const size_t HB = (size_t)BATCH * HIDDEN;          // 131072 elems
    unsigned short* h_hi0 = (unsigned short*)d_ws;
    unsigned short* h_lo0 = h_hi0 + HB;
    unsigned short* h_hi1 = h_lo0 + HB;
    unsigned short* h_lo1 = h_hi1 + HB;
    int* bar = (int*)(h_lo1 + HB);                     // 8 groups x 32 ints (1 KB)
    unsigned short* Bhi = (unsigned short*)((char*)(bar + 256));
    unsigned short* Blo = Bhi + (size_t)NFRAGS * 512;

    // zero h ping/pong (hi/lo, 4 x 256 KB) + barrier state (1 KB)
    hipMemsetAsync(d_ws, 0, HB * 2 * 4 + 1024, stream);
    pack_weights<<<(NFRAGS * 64 + 255) / 256, 256, 0, stream>>>(W, U, Bhi, Blo);

    void* args[] = { (void*)&features, (void*)&actions, (void*)&Bhi, (void*)&Blo,
                     (void*)&bias, (void*)&h_hi0, (void*)&h_lo0, (void*)&h_hi1,
                     (void*)&h_lo1, (void*)&out, (void*)&bar };
    hipLaunchCooperativeKernel((const void*)lstm_persistent,
                               dim3(NGROUPS, BATCH / 32), dim3(256),
                               args, 0, stream);
}